// Round 1
// baseline (320.952 us; speedup 1.0000x reference)
//
#include <hip/hip_runtime.h>
#include <math.h>

typedef unsigned short ushort_t;
typedef unsigned int   uint_t;
typedef __attribute__((ext_vector_type(8)))  short bf16x8;
typedef __attribute__((ext_vector_type(16))) float f32x16;

#define NPTS   65536   // B*P
#define NV     5023
#define LATD   32
#define KF     110
#define FSTR   112     // feat row stride (uints)

__device__ __forceinline__ ushort_t f2bf(float f) {
  union { float f; unsigned u; } x; x.f = f;
  unsigned r = x.u + 0x7fffu + ((x.u >> 16) & 1u);   // RNE
  return (ushort_t)(r >> 16);
}
__device__ __forceinline__ float bf2f(ushort_t u) {
  union { unsigned u; float f; } x; x.u = ((unsigned)u) << 16;
  return x.f;
}
__device__ __forceinline__ uint_t packsplit(float v) {
  const ushort_t h = f2bf(v);
  const ushort_t l = f2bf(v - bf2f(h));
  return (uint_t)h | ((uint_t)l << 16);
}

// weight panels (ushorts/plane), 9 x 16384 = [128n][128k]:
// p0:L0 p1:L1 p2:L2 p3:L3 p4:L4a(initial) p5:L4b(x) p6:L5 p7:L6 p8:L7

// ------------- Kernel 1: NN (4 pts/lane x 16-way split) + features + weight prep -------------
// UNCHANGED from verified baseline (r7-verified metric; do not touch).
__global__ __launch_bounds__(256, 4) void k_nnfeat(
    const float* __restrict__ pts, const float* __restrict__ dm,
    const float* __restrict__ cano, const float* __restrict__ lat,
    const float* __restrict__ w0, const float* __restrict__ w1,
    const float* __restrict__ w2, const float* __restrict__ w3,
    const float* __restrict__ w4, const float* __restrict__ w5,
    const float* __restrict__ w6, const float* __restrict__ w7,
    uint_t* __restrict__ feat, float* __restrict__ base3,
    ushort_t* __restrict__ wsWh, ushort_t* __restrict__ wsWl)
{
  const int tid = threadIdx.x;

  // distributed weight prep: 144 elements per block (1024*144 = 147456)
  if (tid < 144) {
    const int e = blockIdx.x * 144 + tid;
    const int p = e >> 14, local = e & 16383;
    const int n = local >> 7, k = local & 127;
    float v;
    if (p == 0)      v = (k < KF) ? w0[n*110 + k] : 0.f;
    else if (p == 1) v = w1[n*128 + k];
    else if (p == 2) v = w2[n*128 + k];
    else if (p == 3) v = w3[n*128 + k];
    else if (p == 4) v = (k < KF) ? w4[n*238 + k] : 0.f;
    else if (p == 5) v = w4[n*238 + KF + k];
    else if (p == 6) v = w5[n*128 + k];
    else if (p == 7) v = w6[n*128 + k];
    else             v = w7[n*128 + k];
    const ushort_t h = f2bf(v);
    wsWh[e] = h;
    wsWl[e] = f2bf(v - bf2f(h));
  }

  __shared__ float4 sV[512];    // 8 KB vertex chunk
  __shared__ float  sD[64];
  __shared__ int    sI[64];

  const int lane = tid & 63, w = tid >> 6;
  const int slot = lane >> 4, s = lane & 15;
  const int g0 = blockIdx.x * 64;
  const int b  = blockIdx.x >> 9;               // 512 blocks per batch
  const float* __restrict__ dmb = dm + b * NV * 3;
  const int pbase = g0 + w*16 + slot*4;

  float px[4], py[4], pz[4], p2[4], bs[4]; int bi[4];
  #pragma unroll
  for (int j = 0; j < 4; ++j) {
    px[j] = pts[(pbase+j)*3+0]; py[j] = pts[(pbase+j)*3+1]; pz[j] = pts[(pbase+j)*3+2];
    p2[j] = fmaf(px[j],px[j], fmaf(py[j],py[j], pz[j]*pz[j]));
    bs[j] = 3.4e38f; bi[j] = 0;
  }

  for (int v0 = 0; v0 < NV; v0 += 512) {        // 10 chunks
    __syncthreads();
    #pragma unroll
    for (int it = 0; it < 2; ++it) {
      const int i = it*256 + tid;
      const int v = v0 + i;
      float4 t;
      if (v < NV) {
        const float x = dmb[v*3+0], y = dmb[v*3+1], z = dmb[v*3+2];
        t = make_float4(x, y, z, fmaf(x,x, fmaf(y,y, z*z)));
      } else {
        t = make_float4(0.f, 0.f, 0.f, __builtin_inff());
      }
      sV[i] = t;
    }
    __syncthreads();
    #pragma unroll 8
    for (int k = 0; k < 32; ++k) {
      const float4 t = sV[k*16 + s];
      const int vi = v0 + k*16 + s;
      #pragma unroll
      for (int j = 0; j < 4; ++j) {
        const float dot = fmaf(px[j], t.x, fmaf(py[j], t.y, pz[j]*t.z));
        float d2 = fmaf(-2.f, dot, p2[j] + t.w);      // ref formula, r7-verified
        d2 = fmaxf(d2, 0.f);
        if (d2 < bs[j]) { bs[j] = d2; bi[j] = vi; }   // strict < => first index
      }
    }
  }

  // reduce over 16 splits (butterfly, lexicographic (d2, idx) min)
  #pragma unroll
  for (int off = 1; off <= 8; off <<= 1) {
    #pragma unroll
    for (int j = 0; j < 4; ++j) {
      const float ob = __shfl_xor(bs[j], off, 64);
      const int   oi = __shfl_xor(bi[j], off, 64);
      const bool take = (ob < bs[j]) || ((ob == bs[j]) && (oi < bi[j]));
      if (take) { bs[j] = ob; bi[j] = oi; }
    }
  }
  if (s == 0) {
    #pragma unroll
    for (int j = 0; j < 4; ++j) {
      sD[w*16 + slot*4 + j] = bs[j];
      sI[w*16 + slot*4 + j] = bi[j];
    }
  }
  __syncthreads();

  // ---- features: 4 wave-uniform slices per point ----
  const int p = tid & 63, slice = tid >> 6;
  const int g = g0 + p;
  const float wd = sD[p];
  const int   wi = sI[p];

  const float qx = pts[g*3+0], qy = pts[g*3+1], qz = pts[g*3+2];
  const float wgt = expf(-wd);
  const float sx = (cano[wi*3+0] - dmb[wi*3+0]) * wgt;
  const float sy = (cano[wi*3+1] - dmb[wi*3+1]) * wgt;
  const float sz = (cano[wi*3+2] - dmb[wi*3+2]) * wgt;

  uint_t* __restrict__ fr = feat + (size_t)g * FSTR;

  if (slice == 0) {
    base3[g*3+0] = qx + sx; base3[g*3+1] = qy + sy; base3[g*3+2] = qz + sz;
    fr[0] = packsplit(qx); fr[1] = packsplit(qy); fr[2] = packsplit(qz);
    #pragma unroll
    for (int f = 0; f < 3; ++f) {
      const float F = (float)(1 << f);
      float s0,c0,s1,c1,s2,c2;
      sincosf(qx*F,&s0,&c0); sincosf(qy*F,&s1,&c1); sincosf(qz*F,&s2,&c2);
      const int k = 3 + 6*f;
      fr[k+0]=packsplit(s0); fr[k+1]=packsplit(s1); fr[k+2]=packsplit(s2);
      fr[k+3]=packsplit(c0); fr[k+4]=packsplit(c1); fr[k+5]=packsplit(c2);
    }
    fr[110] = 0; fr[111] = 0;
  } else if (slice == 1) {
    #pragma unroll
    for (int f = 3; f < 7; ++f) {
      const float F = (float)(1 << f);
      float s0,c0,s1,c1,s2,c2;
      sincosf(qx*F,&s0,&c0); sincosf(qy*F,&s1,&c1); sincosf(qz*F,&s2,&c2);
      const int k = 3 + 6*f;
      fr[k+0]=packsplit(s0); fr[k+1]=packsplit(s1); fr[k+2]=packsplit(s2);
      fr[k+3]=packsplit(c0); fr[k+4]=packsplit(c1); fr[k+5]=packsplit(c2);
    }
  } else if (slice == 2) {
    #pragma unroll
    for (int f = 7; f < 10; ++f) {
      const float F = (float)(1 << f);
      float s0,c0,s1,c1,s2,c2;
      sincosf(qx*F,&s0,&c0); sincosf(qy*F,&s1,&c1); sincosf(qz*F,&s2,&c2);
      const int k = 3 + 6*f;
      fr[k+0]=packsplit(s0); fr[k+1]=packsplit(s1); fr[k+2]=packsplit(s2);
      fr[k+3]=packsplit(c0); fr[k+4]=packsplit(c1); fr[k+5]=packsplit(c2);
    }
    #pragma unroll
    for (int j = 0; j < 16; ++j) fr[78+j] = packsplit(lat[g*LATD + j]);
  } else {
    fr[63]=packsplit(sx); fr[64]=packsplit(sy); fr[65]=packsplit(sz);
    #pragma unroll
    for (int f = 0; f < 2; ++f) {
      const float F = (float)(1 << f);
      float s0,c0,s1,c1,s2,c2;
      sincosf(sx*F,&s0,&c0); sincosf(sy*F,&s1,&c1); sincosf(sz*F,&s2,&c2);
      const int k = 66 + 6*f;
      fr[k+0]=packsplit(s0); fr[k+1]=packsplit(s1); fr[k+2]=packsplit(s2);
      fr[k+3]=packsplit(c0); fr[k+4]=packsplit(c1); fr[k+5]=packsplit(c2);
    }
    #pragma unroll
    for (int j = 16; j < 32; ++j) fr[78+j] = packsplit(lat[g*LATD + j]);
  }
}

// ------------- Kernel 2: register-resident MLP (operand-swapped MFMA) -------------
// Each wave owns 32 points. D[n][m] = W(A) x X^T(B): C/D col = lane&31 = point, so the
// lane pair (l31, l31+32) holds the full 128-feature activation of point l31 after each
// layer. Next-layer B-frags are built in-register with 4 shfl_xor(32) per k-slab.
// No barriers in the MLP; no LDS for activations; LDS only for bias/w_out staging and
// the final last_feat transpose (per-wave buffer).

union U4 { uint_t u[4]; bf16x8 v; };

__device__ __forceinline__ void zero4(f32x16 (&a)[4]) {
  #pragma unroll
  for (int i = 0; i < 4; ++i) a[i] = (f32x16)(0.f);
}

// feat row (packed h|l<<16 words) -> 7 k-slab frags (k=0..111; words 110,111 are zero)
__device__ __forceinline__ void load_feat_frags(
    const uint_t* __restrict__ fr, bf16x8 (&Xh)[8], bf16x8 (&Xl)[8], int lh)
{
  #pragma unroll
  for (int ks = 0; ks < 7; ++ks) {
    const int k0 = ks*16 + lh*8;
    const uint4 ua = *(const uint4*)(fr + k0);
    const uint4 ub = *(const uint4*)(fr + k0 + 4);
    U4 H, L;
    H.u[0] = (ua.x & 0xffffu) | (ua.y << 16);
    H.u[1] = (ua.z & 0xffffu) | (ua.w << 16);
    H.u[2] = (ub.x & 0xffffu) | (ub.y << 16);
    H.u[3] = (ub.z & 0xffffu) | (ub.w << 16);
    L.u[0] = (ua.x >> 16) | (ua.y & 0xffff0000u);
    L.u[1] = (ua.z >> 16) | (ua.w & 0xffff0000u);
    L.u[2] = (ub.x >> 16) | (ub.y & 0xffff0000u);
    L.u[3] = (ub.z >> 16) | (ub.w & 0xffff0000u);
    Xh[ks] = H.v; Xl[ks] = L.v;
  }
}

// A = weight panel rows n = tn*32 + l31, k = ks*16 + lh*8 + j (global bf16x8 loads).
// bf16x3 products: Wh*Xh + Wl*Xh + Wh*Xl (drop Wl*Xl), same as verified baseline.
template<int NKS>
__device__ __forceinline__ void run_panel(f32x16 (&acc)[4],
    const ushort_t* __restrict__ Wh, const ushort_t* __restrict__ Wl,
    const bf16x8 (&Xh)[8], const bf16x8 (&Xl)[8], int l31, int lh)
{
  #pragma unroll
  for (int ks = 0; ks < NKS; ++ks) {
    const int k0 = ks*16 + lh*8;
    bf16x8 wh[4], wl[4];
    #pragma unroll
    for (int tn = 0; tn < 4; ++tn) {
      const int n = tn*32 + l31;
      wh[tn] = *(const bf16x8*)(Wh + n*128 + k0);
      wl[tn] = *(const bf16x8*)(Wl + n*128 + k0);
    }
    #pragma unroll
    for (int tn = 0; tn < 4; ++tn) {
      acc[tn] = __builtin_amdgcn_mfma_f32_32x32x16_bf16(wh[tn], Xh[ks], acc[tn], 0,0,0);
      acc[tn] = __builtin_amdgcn_mfma_f32_32x32x16_bf16(wl[tn], Xh[ks], acc[tn], 0,0,0);
      acc[tn] = __builtin_amdgcn_mfma_f32_32x32x16_bf16(wh[tn], Xl[ks], acc[tn], 0,0,0);
    }
  }
}

// C/D layout (32x32): col = lane&31, row = (r&3) + 8*(r>>2) + 4*lh
// r = 4b + j  ->  n = tn*32 + 8b + 4*lh + j
__device__ __forceinline__ void bias_relu(f32x16 (&acc)[4],
    const float* __restrict__ bias, int lh)
{
  #pragma unroll
  for (int tn = 0; tn < 4; ++tn)
    #pragma unroll
    for (int b = 0; b < 4; ++b) {
      const float4 b4 = *(const float4*)(bias + tn*32 + 8*b + 4*lh);
      acc[tn][4*b+0] = fmaxf(acc[tn][4*b+0] + b4.x, 0.f);
      acc[tn][4*b+1] = fmaxf(acc[tn][4*b+1] + b4.y, 0.f);
      acc[tn][4*b+2] = fmaxf(acc[tn][4*b+2] + b4.z, 0.f);
      acc[tn][4*b+3] = fmaxf(acc[tn][4*b+3] + b4.w, 0.f);
    }
}

// acc (post bias/relu) -> next-layer B-frags, in-register + half-wave exchange.
// Slab ks consumes tile tn = ks>>1 rows r = 8*(ks&1)+{0..7}:
//   block A (r+0..3): n-in-tile = 16*(ks&1) + 4*lh_src + j   -> serves consumer j0..3 (lh=0) / recv
//   block B (r+4..7): n-in-tile = 16*(ks&1) + 8 + 4*lh_src+j -> serves consumer lh=1 side
// lane lh keeps block (lh?B:A) for itself and sends block (lh?A:B) to lane^32.
__device__ __forceinline__ void build_frags(const f32x16 (&acc)[4],
    bf16x8 (&Xh)[8], bf16x8 (&Xl)[8], int lh)
{
  #pragma unroll
  for (int ks = 0; ks < 8; ++ks) {
    const int tn = ks >> 1;
    const int rb = 8*(ks & 1);
    const float f0 = acc[tn][rb+0], f1 = acc[tn][rb+1];
    const float f2 = acc[tn][rb+2], f3 = acc[tn][rb+3];
    const float f4 = acc[tn][rb+4], f5 = acc[tn][rb+5];
    const float f6 = acc[tn][rb+6], f7 = acc[tn][rb+7];
    const ushort_t h0=f2bf(f0), h1=f2bf(f1), h2=f2bf(f2), h3=f2bf(f3);
    const ushort_t h4=f2bf(f4), h5=f2bf(f5), h6=f2bf(f6), h7=f2bf(f7);
    const uint_t hA0 = (uint_t)h0 | ((uint_t)h1 << 16);
    const uint_t hA1 = (uint_t)h2 | ((uint_t)h3 << 16);
    const uint_t hB0 = (uint_t)h4 | ((uint_t)h5 << 16);
    const uint_t hB1 = (uint_t)h6 | ((uint_t)h7 << 16);
    const uint_t lA0 = (uint_t)f2bf(f0 - bf2f(h0)) | ((uint_t)f2bf(f1 - bf2f(h1)) << 16);
    const uint_t lA1 = (uint_t)f2bf(f2 - bf2f(h2)) | ((uint_t)f2bf(f3 - bf2f(h3)) << 16);
    const uint_t lB0 = (uint_t)f2bf(f4 - bf2f(h4)) | ((uint_t)f2bf(f5 - bf2f(h5)) << 16);
    const uint_t lB1 = (uint_t)f2bf(f6 - bf2f(h6)) | ((uint_t)f2bf(f7 - bf2f(h7)) << 16);
    // send the block the partner needs
    const uint_t sh0 = lh ? hA0 : hB0, sh1 = lh ? hA1 : hB1;
    const uint_t sl0 = lh ? lA0 : lB0, sl1 = lh ? lA1 : lB1;
    const uint_t rh0 = __shfl_xor(sh0, 32, 64), rh1 = __shfl_xor(sh1, 32, 64);
    const uint_t rl0 = __shfl_xor(sl0, 32, 64), rl1 = __shfl_xor(sl1, 32, 64);
    U4 H, L;
    H.u[0] = lh ? rh0 : hA0;  H.u[1] = lh ? rh1 : hA1;
    H.u[2] = lh ? hB0 : rh0;  H.u[3] = lh ? hB1 : rh1;
    L.u[0] = lh ? rl0 : lA0;  L.u[1] = lh ? rl1 : lA1;
    L.u[2] = lh ? lB0 : rl0;  L.u[3] = lh ? lB1 : rl1;
    Xh[ks] = H.v; Xl[ks] = L.v;
  }
}

__global__ __launch_bounds__(256, 2) void k_mlp(
    const uint_t* __restrict__ feat, const float* __restrict__ base3,
    const ushort_t* __restrict__ wsWh, const ushort_t* __restrict__ wsWl,
    const float* __restrict__ b0, const float* __restrict__ b1,
    const float* __restrict__ b2, const float* __restrict__ b3,
    const float* __restrict__ b4, const float* __restrict__ b5,
    const float* __restrict__ b6, const float* __restrict__ b7,
    const float* __restrict__ w_out, const float* __restrict__ b_out,
    float* __restrict__ out)
{
  __shared__ __align__(16) float sF[4][32*132];   // per-wave transpose buf, 67.6 KB
  __shared__ __align__(16) float sB[8*128 + 384 + 4];

  const int tid  = threadIdx.x;
  const int lane = tid & 63, wid = tid >> 6;
  const int l31 = lane & 31, lh = lane >> 5;
  const int p0 = blockIdx.x * 128 + wid * 32;

  // stage biases + w_out + b_out (only cross-wave shared data; single barrier)
  {
    const float* bsp[8] = {b0,b1,b2,b3,b4,b5,b6,b7};
    if (tid < 128) {
      #pragma unroll
      for (int l = 0; l < 8; ++l) sB[l*128 + tid] = bsp[l][tid];
    }
    for (int i = tid; i < 384; i += 256) sB[1024 + i] = w_out[i];
    if (tid < 3) sB[1408 + tid] = b_out[tid];
  }
  __syncthreads();

  const uint_t* __restrict__ fr = feat + (size_t)(p0 + l31) * FSTR;

  bf16x8 Xh[8], Xl[8];
  f32x16 acc[4];

  // L0 (panel 0, 7 slabs: k=112..127 are zero)
  load_feat_frags(fr, Xh, Xl, lh);
  zero4(acc);
  run_panel<7>(acc, wsWh, wsWl, Xh, Xl, l31, lh);
  bias_relu(acc, sB, lh);
  build_frags(acc, Xh, Xl, lh);

  // L1..L3 (panels 1..3)
  {
    const ushort_t* ph = wsWh + 16384;
    const ushort_t* pl = wsWl + 16384;
    const float*    pb = sB + 128;
    #pragma unroll 1
    for (int l = 0; l < 3; ++l) {
      zero4(acc);
      run_panel<8>(acc, ph, pl, Xh, Xl, l31, lh);
      bias_relu(acc, pb, lh);
      build_frags(acc, Xh, Xl, lh);
      ph += 16384; pl += 16384; pb += 128;
    }
  }

  // L4: x part (panel 5), then initial part (panel 4, 7 slabs)
  zero4(acc);
  run_panel<8>(acc, wsWh + 5*16384, wsWl + 5*16384, Xh, Xl, l31, lh);
  load_feat_frags(fr, Xh, Xl, lh);            // Xh/Xl free to reuse now
  run_panel<7>(acc, wsWh + 4*16384, wsWl + 4*16384, Xh, Xl, l31, lh);
  bias_relu(acc, sB + 4*128, lh);
  build_frags(acc, Xh, Xl, lh);

  // L5..L6 (panels 6..7)
  {
    const ushort_t* ph = wsWh + 6*16384;
    const ushort_t* pl = wsWl + 6*16384;
    const float*    pb = sB + 5*128;
    #pragma unroll 1
    for (int l = 0; l < 2; ++l) {
      zero4(acc);
      run_panel<8>(acc, ph, pl, Xh, Xl, l31, lh);
      bias_relu(acc, pb, lh);
      build_frags(acc, Xh, Xl, lh);
      ph += 16384; pl += 16384; pb += 128;
    }
  }

  // L7 (panel 8): pre-activation = last_feat
  zero4(acc);
  run_panel<8>(acc, wsWh + 8*16384, wsWl + 8*16384, Xh, Xl, l31, lh);

  // epilogue: +bias -> sF (pre-act, per-wave), relu in acc
  float* __restrict__ sFw = &sF[wid][0];
  #pragma unroll
  for (int tn = 0; tn < 4; ++tn)
    #pragma unroll
    for (int b = 0; b < 4; ++b) {
      const int n0 = tn*32 + 8*b + 4*lh;
      const float4 bv = *(const float4*)(sB + 7*128 + n0);
      const float v0 = acc[tn][4*b+0] + bv.x;
      const float v1 = acc[tn][4*b+1] + bv.y;
      const float v2 = acc[tn][4*b+2] + bv.z;
      const float v3 = acc[tn][4*b+3] + bv.w;
      *(float4*)(sFw + l31*132 + n0) = make_float4(v0, v1, v2, v3);
      acc[tn][4*b+0] = fmaxf(v0, 0.f);
      acc[tn][4*b+1] = fmaxf(v1, 0.f);
      acc[tn][4*b+2] = fmaxf(v2, 0.f);
      acc[tn][4*b+3] = fmaxf(v3, 0.f);
    }

  // within-wave LDS write->read ordering
  asm volatile("s_waitcnt lgkmcnt(0)" ::: "memory");
  __builtin_amdgcn_sched_barrier(0);

  // coalesced fp32 last_feat store
  float* __restrict__ out1 = out + (size_t)NPTS * 3;
  #pragma unroll
  for (int i = 0; i < 16; ++i) {
    const int idx = i*64 + lane;
    const int p = idx >> 5, q = idx & 31;
    const float4 v = *(const float4*)(sFw + p*132 + q*4);
    *(float4*)(out1 + (size_t)(p0 + p)*128 + q*4) = v;
  }

  // mlp_shift = relu(last_feat) . w_out  (in-register partial + half-wave reduce)
  float dotc[3];
  #pragma unroll
  for (int c = 0; c < 3; ++c) {
    float a = 0.f;
    #pragma unroll
    for (int tn = 0; tn < 4; ++tn)
      #pragma unroll
      for (int b = 0; b < 4; ++b) {
        const int n0 = tn*32 + 8*b + 4*lh;
        const float4 w4 = *(const float4*)(sB + 1024 + c*128 + n0);
        a = fmaf(acc[tn][4*b+0], w4.x, a);
        a = fmaf(acc[tn][4*b+1], w4.y, a);
        a = fmaf(acc[tn][4*b+2], w4.z, a);
        a = fmaf(acc[tn][4*b+3], w4.w, a);
      }
    a += __shfl_xor(a, 32, 64);
    dotc[c] = a;
  }
  if (lh == 0) {
    const int g = p0 + l31;
    #pragma unroll
    for (int c = 0; c < 3; ++c)
      out[g*3 + c] = base3[g*3 + c] + dotc[c] + sB[1408 + c];
  }
}

extern "C" void kernel_launch(void* const* d_in, const int* in_sizes, int n_in,
                              void* d_out, int out_size, void* d_ws, size_t ws_size,
                              hipStream_t stream)
{
  const float* pts  = (const float*)d_in[0];
  const float* dm   = (const float*)d_in[1];
  const float* cano = (const float*)d_in[2];
  const float* lat  = (const float*)d_in[3];
  const float* w[8]; const float* b[8];
  for (int i = 0; i < 8; ++i) {
    w[i] = (const float*)d_in[4 + 2*i];
    b[i] = (const float*)d_in[5 + 2*i];
  }
  const float* w_out = (const float*)d_in[20];
  const float* b_out = (const float*)d_in[21];
  float* out = (float*)d_out;

  // ws: feat [NPTS][112] uint (29.36MB) | base3 (786KB) | wsWh (288KB) | wsWl (288KB)
  uint_t*   feat  = (uint_t*)d_ws;
  float*    base3 = (float*)((char*)d_ws + (size_t)NPTS*FSTR*4);
  ushort_t* wsWh  = (ushort_t*)((char*)base3 + (size_t)NPTS*3*4);
  ushort_t* wsWl  = wsWh + 147456;

  k_nnfeat<<<1024, 256, 0, stream>>>(pts, dm, cano, lat,
      w[0],w[1],w[2],w[3],w[4],w[5],w[6],w[7], feat, base3, wsWh, wsWl);
  k_mlp<<<NPTS/128, 256, 0, stream>>>(feat, base3, wsWh, wsWl,
      b[0],b[1],b[2],b[3],b[4],b[5],b[6],b[7], w_out, b_out, out);
}

// Round 2
// 319.435 us; speedup vs baseline: 1.0047x; 1.0047x over previous
//
#include <hip/hip_runtime.h>
#include <math.h>

typedef unsigned short ushort_t;
typedef unsigned int   uint_t;
typedef __attribute__((ext_vector_type(8)))  short bf16x8;
typedef __attribute__((ext_vector_type(16))) float f32x16;

#define NPTS   65536   // B*P
#define NV     5023
#define LATD   32
#define KF     110
#define FSTR   112     // feat row stride (uints)

__device__ __forceinline__ ushort_t f2bf(float f) {
  union { float f; unsigned u; } x; x.f = f;
  unsigned r = x.u + 0x7fffu + ((x.u >> 16) & 1u);   // RNE
  return (ushort_t)(r >> 16);
}
__device__ __forceinline__ float bf2f(ushort_t u) {
  union { unsigned u; float f; } x; x.u = ((unsigned)u) << 16;
  return x.f;
}
__device__ __forceinline__ uint_t packsplit(float v) {
  const ushort_t h = f2bf(v);
  const ushort_t l = f2bf(v - bf2f(h));
  return (uint_t)h | ((uint_t)l << 16);
}

// weight panels (ushorts/plane), 9 x 16384 = [128n][128k]:
// p0:L0 p1:L1 p2:L2 p3:L3 p4:L4a(initial) p5:L4b(x) p6:L5 p7:L6 p8:L7

// ------------- Kernel 1: NN (4 pts/lane x 16-way split) + features + weight prep -------------
// UNCHANGED from verified baseline (r7-verified metric; do not touch).
__global__ __launch_bounds__(256, 4) void k_nnfeat(
    const float* __restrict__ pts, const float* __restrict__ dm,
    const float* __restrict__ cano, const float* __restrict__ lat,
    const float* __restrict__ w0, const float* __restrict__ w1,
    const float* __restrict__ w2, const float* __restrict__ w3,
    const float* __restrict__ w4, const float* __restrict__ w5,
    const float* __restrict__ w6, const float* __restrict__ w7,
    uint_t* __restrict__ feat, float* __restrict__ base3,
    ushort_t* __restrict__ wsWh, ushort_t* __restrict__ wsWl)
{
  const int tid = threadIdx.x;

  // distributed weight prep: 144 elements per block (1024*144 = 147456)
  if (tid < 144) {
    const int e = blockIdx.x * 144 + tid;
    const int p = e >> 14, local = e & 16383;
    const int n = local >> 7, k = local & 127;
    float v;
    if (p == 0)      v = (k < KF) ? w0[n*110 + k] : 0.f;
    else if (p == 1) v = w1[n*128 + k];
    else if (p == 2) v = w2[n*128 + k];
    else if (p == 3) v = w3[n*128 + k];
    else if (p == 4) v = (k < KF) ? w4[n*238 + k] : 0.f;
    else if (p == 5) v = w4[n*238 + KF + k];
    else if (p == 6) v = w5[n*128 + k];
    else if (p == 7) v = w6[n*128 + k];
    else             v = w7[n*128 + k];
    const ushort_t h = f2bf(v);
    wsWh[e] = h;
    wsWl[e] = f2bf(v - bf2f(h));
  }

  __shared__ float4 sV[512];    // 8 KB vertex chunk
  __shared__ float  sD[64];
  __shared__ int    sI[64];

  const int lane = tid & 63, w = tid >> 6;
  const int slot = lane >> 4, s = lane & 15;
  const int g0 = blockIdx.x * 64;
  const int b  = blockIdx.x >> 9;               // 512 blocks per batch
  const float* __restrict__ dmb = dm + b * NV * 3;
  const int pbase = g0 + w*16 + slot*4;

  float px[4], py[4], pz[4], p2[4], bs[4]; int bi[4];
  #pragma unroll
  for (int j = 0; j < 4; ++j) {
    px[j] = pts[(pbase+j)*3+0]; py[j] = pts[(pbase+j)*3+1]; pz[j] = pts[(pbase+j)*3+2];
    p2[j] = fmaf(px[j],px[j], fmaf(py[j],py[j], pz[j]*pz[j]));
    bs[j] = 3.4e38f; bi[j] = 0;
  }

  for (int v0 = 0; v0 < NV; v0 += 512) {        // 10 chunks
    __syncthreads();
    #pragma unroll
    for (int it = 0; it < 2; ++it) {
      const int i = it*256 + tid;
      const int v = v0 + i;
      float4 t;
      if (v < NV) {
        const float x = dmb[v*3+0], y = dmb[v*3+1], z = dmb[v*3+2];
        t = make_float4(x, y, z, fmaf(x,x, fmaf(y,y, z*z)));
      } else {
        t = make_float4(0.f, 0.f, 0.f, __builtin_inff());
      }
      sV[i] = t;
    }
    __syncthreads();
    #pragma unroll 8
    for (int k = 0; k < 32; ++k) {
      const float4 t = sV[k*16 + s];
      const int vi = v0 + k*16 + s;
      #pragma unroll
      for (int j = 0; j < 4; ++j) {
        const float dot = fmaf(px[j], t.x, fmaf(py[j], t.y, pz[j]*t.z));
        float d2 = fmaf(-2.f, dot, p2[j] + t.w);      // ref formula, r7-verified
        d2 = fmaxf(d2, 0.f);
        if (d2 < bs[j]) { bs[j] = d2; bi[j] = vi; }   // strict < => first index
      }
    }
  }

  // reduce over 16 splits (butterfly, lexicographic (d2, idx) min)
  #pragma unroll
  for (int off = 1; off <= 8; off <<= 1) {
    #pragma unroll
    for (int j = 0; j < 4; ++j) {
      const float ob = __shfl_xor(bs[j], off, 64);
      const int   oi = __shfl_xor(bi[j], off, 64);
      const bool take = (ob < bs[j]) || ((ob == bs[j]) && (oi < bi[j]));
      if (take) { bs[j] = ob; bi[j] = oi; }
    }
  }
  if (s == 0) {
    #pragma unroll
    for (int j = 0; j < 4; ++j) {
      sD[w*16 + slot*4 + j] = bs[j];
      sI[w*16 + slot*4 + j] = bi[j];
    }
  }
  __syncthreads();

  // ---- features: 4 wave-uniform slices per point ----
  const int p = tid & 63, slice = tid >> 6;
  const int g = g0 + p;
  const float wd = sD[p];
  const int   wi = sI[p];

  const float qx = pts[g*3+0], qy = pts[g*3+1], qz = pts[g*3+2];
  const float wgt = expf(-wd);
  const float sx = (cano[wi*3+0] - dmb[wi*3+0]) * wgt;
  const float sy = (cano[wi*3+1] - dmb[wi*3+1]) * wgt;
  const float sz = (cano[wi*3+2] - dmb[wi*3+2]) * wgt;

  uint_t* __restrict__ fr = feat + (size_t)g * FSTR;

  if (slice == 0) {
    base3[g*3+0] = qx + sx; base3[g*3+1] = qy + sy; base3[g*3+2] = qz + sz;
    fr[0] = packsplit(qx); fr[1] = packsplit(qy); fr[2] = packsplit(qz);
    #pragma unroll
    for (int f = 0; f < 3; ++f) {
      const float F = (float)(1 << f);
      float s0,c0,s1,c1,s2,c2;
      sincosf(qx*F,&s0,&c0); sincosf(qy*F,&s1,&c1); sincosf(qz*F,&s2,&c2);
      const int k = 3 + 6*f;
      fr[k+0]=packsplit(s0); fr[k+1]=packsplit(s1); fr[k+2]=packsplit(s2);
      fr[k+3]=packsplit(c0); fr[k+4]=packsplit(c1); fr[k+5]=packsplit(c2);
    }
    fr[110] = 0; fr[111] = 0;
  } else if (slice == 1) {
    #pragma unroll
    for (int f = 3; f < 7; ++f) {
      const float F = (float)(1 << f);
      float s0,c0,s1,c1,s2,c2;
      sincosf(qx*F,&s0,&c0); sincosf(qy*F,&s1,&c1); sincosf(qz*F,&s2,&c2);
      const int k = 3 + 6*f;
      fr[k+0]=packsplit(s0); fr[k+1]=packsplit(s1); fr[k+2]=packsplit(s2);
      fr[k+3]=packsplit(c0); fr[k+4]=packsplit(c1); fr[k+5]=packsplit(c2);
    }
  } else if (slice == 2) {
    #pragma unroll
    for (int f = 7; f < 10; ++f) {
      const float F = (float)(1 << f);
      float s0,c0,s1,c1,s2,c2;
      sincosf(qx*F,&s0,&c0); sincosf(qy*F,&s1,&c1); sincosf(qz*F,&s2,&c2);
      const int k = 3 + 6*f;
      fr[k+0]=packsplit(s0); fr[k+1]=packsplit(s1); fr[k+2]=packsplit(s2);
      fr[k+3]=packsplit(c0); fr[k+4]=packsplit(c1); fr[k+5]=packsplit(c2);
    }
    #pragma unroll
    for (int j = 0; j < 16; ++j) fr[78+j] = packsplit(lat[g*LATD + j]);
  } else {
    fr[63]=packsplit(sx); fr[64]=packsplit(sy); fr[65]=packsplit(sz);
    #pragma unroll
    for (int f = 0; f < 2; ++f) {
      const float F = (float)(1 << f);
      float s0,c0,s1,c1,s2,c2;
      sincosf(sx*F,&s0,&c0); sincosf(sy*F,&s1,&c1); sincosf(sz*F,&s2,&c2);
      const int k = 66 + 6*f;
      fr[k+0]=packsplit(s0); fr[k+1]=packsplit(s1); fr[k+2]=packsplit(s2);
      fr[k+3]=packsplit(c0); fr[k+4]=packsplit(c1); fr[k+5]=packsplit(c2);
    }
    #pragma unroll
    for (int j = 16; j < 32; ++j) fr[78+j] = packsplit(lat[g*LATD + j]);
  }
}

// ------------- Kernel 2: register-resident MLP (operand-swapped MFMA) -------------
// Each wave owns 32 points. D[n][m] = W(A) x X^T(B): C/D col = lane&31 = point, so the
// lane pair (l31, l31+32) holds the full 128-feature activation of point l31 after each
// layer. Next-layer B-frags are built in-register with 4 shfl_xor(32) per k-slab.
// Weight stream is depth-2 software-pipelined in registers: buffer b=ks&1 is consumed
// by slab ks's MFMAs, then refilled with slab ks+2 (or the NEXT panel's slab (ks&1) in
// the last two iterations) so the pipeline never drains across layers.

union U4 { uint_t u[4]; bf16x8 v; };

__device__ __forceinline__ void zero4(f32x16 (&a)[4]) {
  #pragma unroll
  for (int i = 0; i < 4; ++i) a[i] = (f32x16)(0.f);
}

// feat row (packed h|l<<16 words) -> 7 k-slab frags (k=0..111; words 110,111 are zero)
__device__ __forceinline__ void load_feat_frags(
    const uint_t* __restrict__ fr, bf16x8 (&Xh)[8], bf16x8 (&Xl)[8], int lh)
{
  #pragma unroll
  for (int ks = 0; ks < 7; ++ks) {
    const int k0 = ks*16 + lh*8;
    const uint4 ua = *(const uint4*)(fr + k0);
    const uint4 ub = *(const uint4*)(fr + k0 + 4);
    U4 H, L;
    H.u[0] = (ua.x & 0xffffu) | (ua.y << 16);
    H.u[1] = (ua.z & 0xffffu) | (ua.w << 16);
    H.u[2] = (ub.x & 0xffffu) | (ub.y << 16);
    H.u[3] = (ub.z & 0xffffu) | (ub.w << 16);
    L.u[0] = (ua.x >> 16) | (ua.y & 0xffff0000u);
    L.u[1] = (ua.z >> 16) | (ua.w & 0xffff0000u);
    L.u[2] = (ub.x >> 16) | (ub.y & 0xffff0000u);
    L.u[3] = (ub.z >> 16) | (ub.w & 0xffff0000u);
    Xh[ks] = H.v; Xl[ks] = L.v;
  }
}

// load one weight slab (4 n-tiles x h,l) into a register buffer
__device__ __forceinline__ void load_slab(bf16x8 (&wh)[4], bf16x8 (&wl)[4],
    const ushort_t* __restrict__ Wh, const ushort_t* __restrict__ Wl,
    int ks, int l31, int lh)
{
  const int k0 = ks*16 + lh*8;
  #pragma unroll
  for (int tn = 0; tn < 4; ++tn) {
    const int n = tn*32 + l31;
    wh[tn] = *(const bf16x8*)(Wh + n*128 + k0);
    wl[tn] = *(const bf16x8*)(Wl + n*128 + k0);
  }
}

// bf16x3 products: Wh*Xh + Wl*Xh + Wh*Xl (drop Wl*Xl), same as verified baseline.
__device__ __forceinline__ void mfma_slab(f32x16 (&acc)[4],
    const bf16x8 (&wh)[4], const bf16x8 (&wl)[4],
    const bf16x8& xh, const bf16x8& xl)
{
  #pragma unroll
  for (int tn = 0; tn < 4; ++tn) {
    acc[tn] = __builtin_amdgcn_mfma_f32_32x32x16_bf16(wh[tn], xh, acc[tn], 0,0,0);
    acc[tn] = __builtin_amdgcn_mfma_f32_32x32x16_bf16(wl[tn], xh, acc[tn], 0,0,0);
    acc[tn] = __builtin_amdgcn_mfma_f32_32x32x16_bf16(wh[tn], xl, acc[tn], 0,0,0);
  }
}

// Precondition: wbh/wbl[0],[1] hold slabs 0,1 of THIS panel.
// Postcondition (TAIL): wbh/wbl[0],[1] hold slabs 0,1 of the NEXT panel.
// Buffer-parity rule: refill target at iteration ks is b=ks&1; the next-panel slab
// loaded there is s=ks&1 (correct for both NKS=7 and NKS=8 — verified by tracing).
template<int NKS, bool TAIL>
__device__ __forceinline__ void run_panel(f32x16 (&acc)[4],
    const ushort_t* __restrict__ Wh, const ushort_t* __restrict__ Wl,
    const ushort_t* __restrict__ WhN, const ushort_t* __restrict__ WlN,
    bf16x8 (&wbh)[2][4], bf16x8 (&wbl)[2][4],
    const bf16x8 (&Xh)[8], const bf16x8 (&Xl)[8], int l31, int lh)
{
  #pragma unroll
  for (int ks = 0; ks < NKS; ++ks) {
    const int b = ks & 1;
    mfma_slab(acc, wbh[b], wbl[b], Xh[ks], Xl[ks]);
    if (ks + 2 < NKS) {
      load_slab(wbh[b], wbl[b], Wh, Wl, ks + 2, l31, lh);
    } else if (TAIL) {
      load_slab(wbh[b], wbl[b], WhN, WlN, ks & 1, l31, lh);
    }
  }
}

// C/D layout (32x32): col = lane&31, row = (r&3) + 8*(r>>2) + 4*lh
// r = 4b + j  ->  n = tn*32 + 8b + 4*lh + j
__device__ __forceinline__ void bias_relu(f32x16 (&acc)[4],
    const float* __restrict__ bias, int lh)
{
  #pragma unroll
  for (int tn = 0; tn < 4; ++tn)
    #pragma unroll
    for (int b = 0; b < 4; ++b) {
      const float4 b4 = *(const float4*)(bias + tn*32 + 8*b + 4*lh);
      acc[tn][4*b+0] = fmaxf(acc[tn][4*b+0] + b4.x, 0.f);
      acc[tn][4*b+1] = fmaxf(acc[tn][4*b+1] + b4.y, 0.f);
      acc[tn][4*b+2] = fmaxf(acc[tn][4*b+2] + b4.z, 0.f);
      acc[tn][4*b+3] = fmaxf(acc[tn][4*b+3] + b4.w, 0.f);
    }
}

// acc (post bias/relu) -> next-layer B-frags, in-register + half-wave exchange.
// (verified r1: passed with absmax 0.015625)
__device__ __forceinline__ void build_frags(const f32x16 (&acc)[4],
    bf16x8 (&Xh)[8], bf16x8 (&Xl)[8], int lh)
{
  #pragma unroll
  for (int ks = 0; ks < 8; ++ks) {
    const int tn = ks >> 1;
    const int rb = 8*(ks & 1);
    const float f0 = acc[tn][rb+0], f1 = acc[tn][rb+1];
    const float f2 = acc[tn][rb+2], f3 = acc[tn][rb+3];
    const float f4 = acc[tn][rb+4], f5 = acc[tn][rb+5];
    const float f6 = acc[tn][rb+6], f7 = acc[tn][rb+7];
    const ushort_t h0=f2bf(f0), h1=f2bf(f1), h2=f2bf(f2), h3=f2bf(f3);
    const ushort_t h4=f2bf(f4), h5=f2bf(f5), h6=f2bf(f6), h7=f2bf(f7);
    const uint_t hA0 = (uint_t)h0 | ((uint_t)h1 << 16);
    const uint_t hA1 = (uint_t)h2 | ((uint_t)h3 << 16);
    const uint_t hB0 = (uint_t)h4 | ((uint_t)h5 << 16);
    const uint_t hB1 = (uint_t)h6 | ((uint_t)h7 << 16);
    const uint_t lA0 = (uint_t)f2bf(f0 - bf2f(h0)) | ((uint_t)f2bf(f1 - bf2f(h1)) << 16);
    const uint_t lA1 = (uint_t)f2bf(f2 - bf2f(h2)) | ((uint_t)f2bf(f3 - bf2f(h3)) << 16);
    const uint_t lB0 = (uint_t)f2bf(f4 - bf2f(h4)) | ((uint_t)f2bf(f5 - bf2f(h5)) << 16);
    const uint_t lB1 = (uint_t)f2bf(f6 - bf2f(h6)) | ((uint_t)f2bf(f7 - bf2f(h7)) << 16);
    // send the block the partner needs
    const uint_t sh0 = lh ? hA0 : hB0, sh1 = lh ? hA1 : hB1;
    const uint_t sl0 = lh ? lA0 : lB0, sl1 = lh ? lA1 : lB1;
    const uint_t rh0 = __shfl_xor(sh0, 32, 64), rh1 = __shfl_xor(sh1, 32, 64);
    const uint_t rl0 = __shfl_xor(sl0, 32, 64), rl1 = __shfl_xor(sl1, 32, 64);
    U4 H, L;
    H.u[0] = lh ? rh0 : hA0;  H.u[1] = lh ? rh1 : hA1;
    H.u[2] = lh ? hB0 : rh0;  H.u[3] = lh ? hB1 : rh1;
    L.u[0] = lh ? rl0 : lA0;  L.u[1] = lh ? rl1 : lA1;
    L.u[2] = lh ? lB0 : rl0;  L.u[3] = lh ? lB1 : rl1;
    Xh[ks] = H.v; Xl[ks] = L.v;
  }
}

__global__ __launch_bounds__(256, 2) void k_mlp(
    const uint_t* __restrict__ feat, const float* __restrict__ base3,
    const ushort_t* __restrict__ wsWh, const ushort_t* __restrict__ wsWl,
    const float* __restrict__ b0, const float* __restrict__ b1,
    const float* __restrict__ b2, const float* __restrict__ b3,
    const float* __restrict__ b4, const float* __restrict__ b5,
    const float* __restrict__ b6, const float* __restrict__ b7,
    const float* __restrict__ w_out, const float* __restrict__ b_out,
    float* __restrict__ out)
{
  __shared__ __align__(16) float sF[4][32*132];   // per-wave transpose buf, 67.6 KB
  __shared__ __align__(16) float sB[8*128 + 384 + 4];

  const int tid  = threadIdx.x;
  const int lane = tid & 63, wid = tid >> 6;
  const int l31 = lane & 31, lh = lane >> 5;
  const int p0 = blockIdx.x * 128 + wid * 32;

  // stage biases + w_out + b_out (only cross-wave shared data; single barrier)
  {
    const float* bsp[8] = {b0,b1,b2,b3,b4,b5,b6,b7};
    if (tid < 128) {
      #pragma unroll
      for (int l = 0; l < 8; ++l) sB[l*128 + tid] = bsp[l][tid];
    }
    for (int i = tid; i < 384; i += 256) sB[1024 + i] = w_out[i];
    if (tid < 3) sB[1408 + tid] = b_out[tid];
  }

  const uint_t* __restrict__ fr = feat + (size_t)(p0 + l31) * FSTR;

  bf16x8 Xh[8], Xl[8];
  bf16x8 wbh[2][4], wbl[2][4];
  f32x16 acc[4];

  // prime the weight pipeline (p0 slabs 0,1), then feat loads + unpack cover latency
  load_slab(wbh[0], wbl[0], wsWh, wsWl, 0, l31, lh);
  load_slab(wbh[1], wbl[1], wsWh, wsWl, 1, l31, lh);
  load_feat_frags(fr, Xh, Xl, lh);
  __syncthreads();   // sB ready (placed after load issue so it doesn't serialize them)

  // L0 (panel 0, 7 slabs) -> preloads p1
  zero4(acc);
  run_panel<7,true>(acc, wsWh + 0*16384, wsWl + 0*16384,
                         wsWh + 1*16384, wsWl + 1*16384, wbh, wbl, Xh, Xl, l31, lh);
  bias_relu(acc, sB + 0*128, lh);
  build_frags(acc, Xh, Xl, lh);

  // L1 (p1) -> preloads p2
  zero4(acc);
  run_panel<8,true>(acc, wsWh + 1*16384, wsWl + 1*16384,
                         wsWh + 2*16384, wsWl + 2*16384, wbh, wbl, Xh, Xl, l31, lh);
  bias_relu(acc, sB + 1*128, lh);
  build_frags(acc, Xh, Xl, lh);

  // L2 (p2) -> preloads p3
  zero4(acc);
  run_panel<8,true>(acc, wsWh + 2*16384, wsWl + 2*16384,
                         wsWh + 3*16384, wsWl + 3*16384, wbh, wbl, Xh, Xl, l31, lh);
  bias_relu(acc, sB + 2*128, lh);
  build_frags(acc, Xh, Xl, lh);

  // L3 (p3) -> preloads p5 (L4's x-part comes first)
  zero4(acc);
  run_panel<8,true>(acc, wsWh + 3*16384, wsWl + 3*16384,
                         wsWh + 5*16384, wsWl + 5*16384, wbh, wbl, Xh, Xl, l31, lh);
  bias_relu(acc, sB + 3*128, lh);
  build_frags(acc, Xh, Xl, lh);

  // L4 x-part (p5) -> preloads p4; then reload initial feats, accumulate p4 -> preloads p6
  zero4(acc);
  run_panel<8,true>(acc, wsWh + 5*16384, wsWl + 5*16384,
                         wsWh + 4*16384, wsWl + 4*16384, wbh, wbl, Xh, Xl, l31, lh);
  load_feat_frags(fr, Xh, Xl, lh);            // Xh/Xl free to reuse now
  run_panel<7,true>(acc, wsWh + 4*16384, wsWl + 4*16384,
                         wsWh + 6*16384, wsWl + 6*16384, wbh, wbl, Xh, Xl, l31, lh);
  bias_relu(acc, sB + 4*128, lh);
  build_frags(acc, Xh, Xl, lh);

  // L5 (p6) -> preloads p7
  zero4(acc);
  run_panel<8,true>(acc, wsWh + 6*16384, wsWl + 6*16384,
                         wsWh + 7*16384, wsWl + 7*16384, wbh, wbl, Xh, Xl, l31, lh);
  bias_relu(acc, sB + 5*128, lh);
  build_frags(acc, Xh, Xl, lh);

  // L6 (p7) -> preloads p8
  zero4(acc);
  run_panel<8,true>(acc, wsWh + 7*16384, wsWl + 7*16384,
                         wsWh + 8*16384, wsWl + 8*16384, wbh, wbl, Xh, Xl, l31, lh);
  bias_relu(acc, sB + 6*128, lh);
  build_frags(acc, Xh, Xl, lh);

  // L7 (p8, last): pre-activation = last_feat
  zero4(acc);
  run_panel<8,false>(acc, wsWh + 8*16384, wsWl + 8*16384,
                          (const ushort_t*)0, (const ushort_t*)0, wbh, wbl, Xh, Xl, l31, lh);

  // epilogue: +bias -> sF (pre-act, per-wave), relu in acc
  float* __restrict__ sFw = &sF[wid][0];
  #pragma unroll
  for (int tn = 0; tn < 4; ++tn)
    #pragma unroll
    for (int b = 0; b < 4; ++b) {
      const int n0 = tn*32 + 8*b + 4*lh;
      const float4 bv = *(const float4*)(sB + 7*128 + n0);
      const float v0 = acc[tn][4*b+0] + bv.x;
      const float v1 = acc[tn][4*b+1] + bv.y;
      const float v2 = acc[tn][4*b+2] + bv.z;
      const float v3 = acc[tn][4*b+3] + bv.w;
      *(float4*)(sFw + l31*132 + n0) = make_float4(v0, v1, v2, v3);
      acc[tn][4*b+0] = fmaxf(v0, 0.f);
      acc[tn][4*b+1] = fmaxf(v1, 0.f);
      acc[tn][4*b+2] = fmaxf(v2, 0.f);
      acc[tn][4*b+3] = fmaxf(v3, 0.f);
    }

  // within-wave LDS write->read ordering
  asm volatile("s_waitcnt lgkmcnt(0)" ::: "memory");
  __builtin_amdgcn_sched_barrier(0);

  // coalesced fp32 last_feat store
  float* __restrict__ out1 = out + (size_t)NPTS * 3;
  #pragma unroll
  for (int i = 0; i < 16; ++i) {
    const int idx = i*64 + lane;
    const int p = idx >> 5, q = idx & 31;
    const float4 v = *(const float4*)(sFw + p*132 + q*4);
    *(float4*)(out1 + (size_t)(p0 + p)*128 + q*4) = v;
  }

  // mlp_shift = relu(last_feat) . w_out  (in-register partial + half-wave reduce)
  float dotc[3];
  #pragma unroll
  for (int c = 0; c < 3; ++c) {
    float a = 0.f;
    #pragma unroll
    for (int tn = 0; tn < 4; ++tn)
      #pragma unroll
      for (int b = 0; b < 4; ++b) {
        const int n0 = tn*32 + 8*b + 4*lh;
        const float4 w4 = *(const float4*)(sB + 1024 + c*128 + n0);
        a = fmaf(acc[tn][4*b+0], w4.x, a);
        a = fmaf(acc[tn][4*b+1], w4.y, a);
        a = fmaf(acc[tn][4*b+2], w4.z, a);
        a = fmaf(acc[tn][4*b+3], w4.w, a);
      }
    a += __shfl_xor(a, 32, 64);
    dotc[c] = a;
  }
  if (lh == 0) {
    const int g = p0 + l31;
    #pragma unroll
    for (int c = 0; c < 3; ++c)
      out[g*3 + c] = base3[g*3 + c] + dotc[c] + sB[1408 + c];
  }
}

extern "C" void kernel_launch(void* const* d_in, const int* in_sizes, int n_in,
                              void* d_out, int out_size, void* d_ws, size_t ws_size,
                              hipStream_t stream)
{
  const float* pts  = (const float*)d_in[0];
  const float* dm   = (const float*)d_in[1];
  const float* cano = (const float*)d_in[2];
  const float* lat  = (const float*)d_in[3];
  const float* w[8]; const float* b[8];
  for (int i = 0; i < 8; ++i) {
    w[i] = (const float*)d_in[4 + 2*i];
    b[i] = (const float*)d_in[5 + 2*i];
  }
  const float* w_out = (const float*)d_in[20];
  const float* b_out = (const float*)d_in[21];
  float* out = (float*)d_out;

  // ws: feat [NPTS][112] uint (29.36MB) | base3 (786KB) | wsWh (288KB) | wsWl (288KB)
  uint_t*   feat  = (uint_t*)d_ws;
  float*    base3 = (float*)((char*)d_ws + (size_t)NPTS*FSTR*4);
  ushort_t* wsWh  = (ushort_t*)((char*)base3 + (size_t)NPTS*3*4);
  ushort_t* wsWl  = wsWh + 147456;

  k_nnfeat<<<1024, 256, 0, stream>>>(pts, dm, cano, lat,
      w[0],w[1],w[2],w[3],w[4],w[5],w[6],w[7], feat, base3, wsWh, wsWl);
  k_mlp<<<NPTS/128, 256, 0, stream>>>(feat, base3, wsWh, wsWl,
      b[0],b[1],b[2],b[3],b[4],b[5],b[6],b[7], w_out, b_out, out);
}

// Round 3
// 252.227 us; speedup vs baseline: 1.2725x; 1.2665x over previous
//
#include <hip/hip_runtime.h>
#include <math.h>

typedef unsigned short ushort_t;
typedef unsigned int   uint_t;
typedef __attribute__((ext_vector_type(8)))  short bf16x8;
typedef __attribute__((ext_vector_type(16))) float f32x16;

#define NPTS   65536   // B*P
#define NV     5023
#define LATD   32
#define KF     110
#define FSTR   112     // feat row stride (uints)

__device__ __forceinline__ ushort_t f2bf(float f) {
  union { float f; unsigned u; } x; x.f = f;
  unsigned r = x.u + 0x7fffu + ((x.u >> 16) & 1u);   // RNE
  return (ushort_t)(r >> 16);
}
__device__ __forceinline__ float bf2f(ushort_t u) {
  union { unsigned u; float f; } x; x.u = ((unsigned)u) << 16;
  return x.f;
}
__device__ __forceinline__ uint_t packsplit(float v) {
  const ushort_t h = f2bf(v);
  const ushort_t l = f2bf(v - bf2f(h));
  return (uint_t)h | ((uint_t)l << 16);
}

// weight panels (ushorts/plane), 9 x 16384, COALESCED layout:
//   offset(ks,tn,l31,lh,j) = (ks*4+tn)*512 + l31*16 + lh*8 + j
//   holds W[n=tn*32+l31][k=ks*16+lh*8+j]
// -> a wave's load of slab (ks,tn) is one contiguous, aligned 1 KB segment.
// p0:L0 p1:L1 p2:L2 p3:L3 p4:L4a(initial) p5:L4b(x) p6:L5 p7:L6 p8:L7

// ------------- Kernel 1: NN (4 pts/lane x 16-way split) + features + weight prep -------------
// NN/feature part UNCHANGED from verified baseline (r7-verified metric; do not touch).
__global__ __launch_bounds__(256, 4) void k_nnfeat(
    const float* __restrict__ pts, const float* __restrict__ dm,
    const float* __restrict__ cano, const float* __restrict__ lat,
    const float* __restrict__ w0, const float* __restrict__ w1,
    const float* __restrict__ w2, const float* __restrict__ w3,
    const float* __restrict__ w4, const float* __restrict__ w5,
    const float* __restrict__ w6, const float* __restrict__ w7,
    uint_t* __restrict__ feat, float* __restrict__ base3,
    ushort_t* __restrict__ wsWh, ushort_t* __restrict__ wsWl)
{
  const int tid = threadIdx.x;

  // distributed weight prep: 144 elements per block (1024*144 = 147456)
  // decode e -> (panel, ks, tn, l31, lh, j) per the coalesced layout above
  if (tid < 144) {
    const int e = blockIdx.x * 144 + tid;
    const int p = e >> 14, local = e & 16383;
    const int j   = local & 7;
    const int lh  = (local >> 3) & 1;
    const int l31 = (local >> 4) & 31;
    const int tn  = (local >> 9) & 3;
    const int ks  = (local >> 11) & 7;
    const int n = tn*32 + l31;
    const int k = ks*16 + lh*8 + j;
    float v;
    if (p == 0)      v = (k < KF) ? w0[n*110 + k] : 0.f;
    else if (p == 1) v = w1[n*128 + k];
    else if (p == 2) v = w2[n*128 + k];
    else if (p == 3) v = w3[n*128 + k];
    else if (p == 4) v = (k < KF) ? w4[n*238 + k] : 0.f;
    else if (p == 5) v = w4[n*238 + KF + k];
    else if (p == 6) v = w5[n*128 + k];
    else if (p == 7) v = w6[n*128 + k];
    else             v = w7[n*128 + k];
    const ushort_t h = f2bf(v);
    wsWh[e] = h;
    wsWl[e] = f2bf(v - bf2f(h));
  }

  __shared__ float4 sV[512];    // 8 KB vertex chunk
  __shared__ float  sD[64];
  __shared__ int    sI[64];

  const int lane = tid & 63, w = tid >> 6;
  const int slot = lane >> 4, s = lane & 15;
  const int g0 = blockIdx.x * 64;
  const int b  = blockIdx.x >> 9;               // 512 blocks per batch
  const float* __restrict__ dmb = dm + b * NV * 3;
  const int pbase = g0 + w*16 + slot*4;

  float px[4], py[4], pz[4], p2[4], bs[4]; int bi[4];
  #pragma unroll
  for (int j = 0; j < 4; ++j) {
    px[j] = pts[(pbase+j)*3+0]; py[j] = pts[(pbase+j)*3+1]; pz[j] = pts[(pbase+j)*3+2];
    p2[j] = fmaf(px[j],px[j], fmaf(py[j],py[j], pz[j]*pz[j]));
    bs[j] = 3.4e38f; bi[j] = 0;
  }

  for (int v0 = 0; v0 < NV; v0 += 512) {        // 10 chunks
    __syncthreads();
    #pragma unroll
    for (int it = 0; it < 2; ++it) {
      const int i = it*256 + tid;
      const int v = v0 + i;
      float4 t;
      if (v < NV) {
        const float x = dmb[v*3+0], y = dmb[v*3+1], z = dmb[v*3+2];
        t = make_float4(x, y, z, fmaf(x,x, fmaf(y,y, z*z)));
      } else {
        t = make_float4(0.f, 0.f, 0.f, __builtin_inff());
      }
      sV[i] = t;
    }
    __syncthreads();
    #pragma unroll 8
    for (int k = 0; k < 32; ++k) {
      const float4 t = sV[k*16 + s];
      const int vi = v0 + k*16 + s;
      #pragma unroll
      for (int j = 0; j < 4; ++j) {
        const float dot = fmaf(px[j], t.x, fmaf(py[j], t.y, pz[j]*t.z));
        float d2 = fmaf(-2.f, dot, p2[j] + t.w);      // ref formula, r7-verified
        d2 = fmaxf(d2, 0.f);
        if (d2 < bs[j]) { bs[j] = d2; bi[j] = vi; }   // strict < => first index
      }
    }
  }

  // reduce over 16 splits (butterfly, lexicographic (d2, idx) min)
  #pragma unroll
  for (int off = 1; off <= 8; off <<= 1) {
    #pragma unroll
    for (int j = 0; j < 4; ++j) {
      const float ob = __shfl_xor(bs[j], off, 64);
      const int   oi = __shfl_xor(bi[j], off, 64);
      const bool take = (ob < bs[j]) || ((ob == bs[j]) && (oi < bi[j]));
      if (take) { bs[j] = ob; bi[j] = oi; }
    }
  }
  if (s == 0) {
    #pragma unroll
    for (int j = 0; j < 4; ++j) {
      sD[w*16 + slot*4 + j] = bs[j];
      sI[w*16 + slot*4 + j] = bi[j];
    }
  }
  __syncthreads();

  // ---- features: 4 wave-uniform slices per point ----
  const int p = tid & 63, slice = tid >> 6;
  const int g = g0 + p;
  const float wd = sD[p];
  const int   wi = sI[p];

  const float qx = pts[g*3+0], qy = pts[g*3+1], qz = pts[g*3+2];
  const float wgt = expf(-wd);
  const float sx = (cano[wi*3+0] - dmb[wi*3+0]) * wgt;
  const float sy = (cano[wi*3+1] - dmb[wi*3+1]) * wgt;
  const float sz = (cano[wi*3+2] - dmb[wi*3+2]) * wgt;

  uint_t* __restrict__ fr = feat + (size_t)g * FSTR;

  if (slice == 0) {
    base3[g*3+0] = qx + sx; base3[g*3+1] = qy + sy; base3[g*3+2] = qz + sz;
    fr[0] = packsplit(qx); fr[1] = packsplit(qy); fr[2] = packsplit(qz);
    #pragma unroll
    for (int f = 0; f < 3; ++f) {
      const float F = (float)(1 << f);
      float s0,c0,s1,c1,s2,c2;
      sincosf(qx*F,&s0,&c0); sincosf(qy*F,&s1,&c1); sincosf(qz*F,&s2,&c2);
      const int k = 3 + 6*f;
      fr[k+0]=packsplit(s0); fr[k+1]=packsplit(s1); fr[k+2]=packsplit(s2);
      fr[k+3]=packsplit(c0); fr[k+4]=packsplit(c1); fr[k+5]=packsplit(c2);
    }
    fr[110] = 0; fr[111] = 0;
  } else if (slice == 1) {
    #pragma unroll
    for (int f = 3; f < 7; ++f) {
      const float F = (float)(1 << f);
      float s0,c0,s1,c1,s2,c2;
      sincosf(qx*F,&s0,&c0); sincosf(qy*F,&s1,&c1); sincosf(qz*F,&s2,&c2);
      const int k = 3 + 6*f;
      fr[k+0]=packsplit(s0); fr[k+1]=packsplit(s1); fr[k+2]=packsplit(s2);
      fr[k+3]=packsplit(c0); fr[k+4]=packsplit(c1); fr[k+5]=packsplit(c2);
    }
  } else if (slice == 2) {
    #pragma unroll
    for (int f = 7; f < 10; ++f) {
      const float F = (float)(1 << f);
      float s0,c0,s1,c1,s2,c2;
      sincosf(qx*F,&s0,&c0); sincosf(qy*F,&s1,&c1); sincosf(qz*F,&s2,&c2);
      const int k = 3 + 6*f;
      fr[k+0]=packsplit(s0); fr[k+1]=packsplit(s1); fr[k+2]=packsplit(s2);
      fr[k+3]=packsplit(c0); fr[k+4]=packsplit(c1); fr[k+5]=packsplit(c2);
    }
    #pragma unroll
    for (int j = 0; j < 16; ++j) fr[78+j] = packsplit(lat[g*LATD + j]);
  } else {
    fr[63]=packsplit(sx); fr[64]=packsplit(sy); fr[65]=packsplit(sz);
    #pragma unroll
    for (int f = 0; f < 2; ++f) {
      const float F = (float)(1 << f);
      float s0,c0,s1,c1,s2,c2;
      sincosf(sx*F,&s0,&c0); sincosf(sy*F,&s1,&c1); sincosf(sz*F,&s2,&c2);
      const int k = 66 + 6*f;
      fr[k+0]=packsplit(s0); fr[k+1]=packsplit(s1); fr[k+2]=packsplit(s2);
      fr[k+3]=packsplit(c0); fr[k+4]=packsplit(c1); fr[k+5]=packsplit(c2);
    }
    #pragma unroll
    for (int j = 16; j < 32; ++j) fr[78+j] = packsplit(lat[g*LATD + j]);
  }
}

// ------------- Kernel 2: register-resident MLP (operand-swapped MFMA) -------------
// Each wave owns 32 points. D[n][m] = W(A) x X^T(B): C/D col = lane&31 = point, so the
// lane pair (l31, l31+32) holds the full 128-feature activation of point l31 after each
// layer. Next-layer B-frags are built in-register with 4 shfl_xor(32) per k-slab.
// Weight stream: coalesced layout (1 KB/instr) + depth-2 register pipeline; buffer
// b=ks&1 is consumed by slab ks, refilled with slab ks+2 (or next panel's slab ks&1).

union U4 { uint_t u[4]; bf16x8 v; };

__device__ __forceinline__ void zero4(f32x16 (&a)[4]) {
  #pragma unroll
  for (int i = 0; i < 4; ++i) a[i] = (f32x16)(0.f);
}

// feat row (packed h|l<<16 words) -> 7 k-slab frags (k=0..111; words 110,111 are zero)
__device__ __forceinline__ void load_feat_frags(
    const uint_t* __restrict__ fr, bf16x8 (&Xh)[8], bf16x8 (&Xl)[8], int lh)
{
  #pragma unroll
  for (int ks = 0; ks < 7; ++ks) {
    const int k0 = ks*16 + lh*8;
    const uint4 ua = *(const uint4*)(fr + k0);
    const uint4 ub = *(const uint4*)(fr + k0 + 4);
    U4 H, L;
    H.u[0] = (ua.x & 0xffffu) | (ua.y << 16);
    H.u[1] = (ua.z & 0xffffu) | (ua.w << 16);
    H.u[2] = (ub.x & 0xffffu) | (ub.y << 16);
    H.u[3] = (ub.z & 0xffffu) | (ub.w << 16);
    L.u[0] = (ua.x >> 16) | (ua.y & 0xffff0000u);
    L.u[1] = (ua.z >> 16) | (ua.w & 0xffff0000u);
    L.u[2] = (ub.x >> 16) | (ub.y & 0xffff0000u);
    L.u[3] = (ub.z >> 16) | (ub.w & 0xffff0000u);
    Xh[ks] = H.v; Xl[ks] = L.v;
  }
}

// load one weight slab (4 n-tiles x h,l) — coalesced: each instr reads a 1 KB segment
__device__ __forceinline__ void load_slab(bf16x8 (&wh)[4], bf16x8 (&wl)[4],
    const ushort_t* __restrict__ Wh, const ushort_t* __restrict__ Wl,
    int ks, int l31, int lh)
{
  const int lo = l31*16 + lh*8;
  #pragma unroll
  for (int tn = 0; tn < 4; ++tn) {
    const int off = (ks*4 + tn)*512 + lo;
    wh[tn] = *(const bf16x8*)(Wh + off);
    wl[tn] = *(const bf16x8*)(Wl + off);
  }
}

// bf16x3 products: Wh*Xh + Wl*Xh + Wh*Xl (drop Wl*Xl), same as verified baseline.
__device__ __forceinline__ void mfma_slab(f32x16 (&acc)[4],
    const bf16x8 (&wh)[4], const bf16x8 (&wl)[4],
    const bf16x8& xh, const bf16x8& xl)
{
  #pragma unroll
  for (int tn = 0; tn < 4; ++tn) {
    acc[tn] = __builtin_amdgcn_mfma_f32_32x32x16_bf16(wh[tn], xh, acc[tn], 0,0,0);
    acc[tn] = __builtin_amdgcn_mfma_f32_32x32x16_bf16(wl[tn], xh, acc[tn], 0,0,0);
    acc[tn] = __builtin_amdgcn_mfma_f32_32x32x16_bf16(wh[tn], xl, acc[tn], 0,0,0);
  }
}

// Precondition: wbh/wbl[0],[1] hold slabs 0,1 of THIS panel.
// Postcondition (TAIL): wbh/wbl[0],[1] hold slabs 0,1 of the NEXT panel.
// Buffer-parity rule: refill target at iteration ks is b=ks&1; the next-panel slab
// loaded there is s=ks&1 (correct for both NKS=7 and NKS=8 — verified by tracing).
template<int NKS, bool TAIL>
__device__ __forceinline__ void run_panel(f32x16 (&acc)[4],
    const ushort_t* __restrict__ Wh, const ushort_t* __restrict__ Wl,
    const ushort_t* __restrict__ WhN, const ushort_t* __restrict__ WlN,
    bf16x8 (&wbh)[2][4], bf16x8 (&wbl)[2][4],
    const bf16x8 (&Xh)[8], const bf16x8 (&Xl)[8], int l31, int lh)
{
  #pragma unroll
  for (int ks = 0; ks < NKS; ++ks) {
    const int b = ks & 1;
    mfma_slab(acc, wbh[b], wbl[b], Xh[ks], Xl[ks]);
    if (ks + 2 < NKS) {
      load_slab(wbh[b], wbl[b], Wh, Wl, ks + 2, l31, lh);
    } else if (TAIL) {
      load_slab(wbh[b], wbl[b], WhN, WlN, ks & 1, l31, lh);
    }
  }
}

// C/D layout (32x32): col = lane&31, row = (r&3) + 8*(r>>2) + 4*lh
// r = 4b + j  ->  n = tn*32 + 8b + 4*lh + j
__device__ __forceinline__ void bias_relu(f32x16 (&acc)[4],
    const float* __restrict__ bias, int lh)
{
  #pragma unroll
  for (int tn = 0; tn < 4; ++tn)
    #pragma unroll
    for (int b = 0; b < 4; ++b) {
      const float4 b4 = *(const float4*)(bias + tn*32 + 8*b + 4*lh);
      acc[tn][4*b+0] = fmaxf(acc[tn][4*b+0] + b4.x, 0.f);
      acc[tn][4*b+1] = fmaxf(acc[tn][4*b+1] + b4.y, 0.f);
      acc[tn][4*b+2] = fmaxf(acc[tn][4*b+2] + b4.z, 0.f);
      acc[tn][4*b+3] = fmaxf(acc[tn][4*b+3] + b4.w, 0.f);
    }
}

// acc (post bias/relu) -> next-layer B-frags, in-register + half-wave exchange.
// (verified r1: passed with absmax 0.015625)
__device__ __forceinline__ void build_frags(const f32x16 (&acc)[4],
    bf16x8 (&Xh)[8], bf16x8 (&Xl)[8], int lh)
{
  #pragma unroll
  for (int ks = 0; ks < 8; ++ks) {
    const int tn = ks >> 1;
    const int rb = 8*(ks & 1);
    const float f0 = acc[tn][rb+0], f1 = acc[tn][rb+1];
    const float f2 = acc[tn][rb+2], f3 = acc[tn][rb+3];
    const float f4 = acc[tn][rb+4], f5 = acc[tn][rb+5];
    const float f6 = acc[tn][rb+6], f7 = acc[tn][rb+7];
    const ushort_t h0=f2bf(f0), h1=f2bf(f1), h2=f2bf(f2), h3=f2bf(f3);
    const ushort_t h4=f2bf(f4), h5=f2bf(f5), h6=f2bf(f6), h7=f2bf(f7);
    const uint_t hA0 = (uint_t)h0 | ((uint_t)h1 << 16);
    const uint_t hA1 = (uint_t)h2 | ((uint_t)h3 << 16);
    const uint_t hB0 = (uint_t)h4 | ((uint_t)h5 << 16);
    const uint_t hB1 = (uint_t)h6 | ((uint_t)h7 << 16);
    const uint_t lA0 = (uint_t)f2bf(f0 - bf2f(h0)) | ((uint_t)f2bf(f1 - bf2f(h1)) << 16);
    const uint_t lA1 = (uint_t)f2bf(f2 - bf2f(h2)) | ((uint_t)f2bf(f3 - bf2f(h3)) << 16);
    const uint_t lB0 = (uint_t)f2bf(f4 - bf2f(h4)) | ((uint_t)f2bf(f5 - bf2f(h5)) << 16);
    const uint_t lB1 = (uint_t)f2bf(f6 - bf2f(h6)) | ((uint_t)f2bf(f7 - bf2f(h7)) << 16);
    // send the block the partner needs
    const uint_t sh0 = lh ? hA0 : hB0, sh1 = lh ? hA1 : hB1;
    const uint_t sl0 = lh ? lA0 : lB0, sl1 = lh ? lA1 : lB1;
    const uint_t rh0 = __shfl_xor(sh0, 32, 64), rh1 = __shfl_xor(sh1, 32, 64);
    const uint_t rl0 = __shfl_xor(sl0, 32, 64), rl1 = __shfl_xor(sl1, 32, 64);
    U4 H, L;
    H.u[0] = lh ? rh0 : hA0;  H.u[1] = lh ? rh1 : hA1;
    H.u[2] = lh ? hB0 : rh0;  H.u[3] = lh ? hB1 : rh1;
    L.u[0] = lh ? rl0 : lA0;  L.u[1] = lh ? rl1 : lA1;
    L.u[2] = lh ? lB0 : rl0;  L.u[3] = lh ? lB1 : rl1;
    Xh[ks] = H.v; Xl[ks] = L.v;
  }
}

__global__ __launch_bounds__(256, 2) void k_mlp(
    const uint_t* __restrict__ feat, const float* __restrict__ base3,
    const ushort_t* __restrict__ wsWh, const ushort_t* __restrict__ wsWl,
    const float* __restrict__ b0, const float* __restrict__ b1,
    const float* __restrict__ b2, const float* __restrict__ b3,
    const float* __restrict__ b4, const float* __restrict__ b5,
    const float* __restrict__ b6, const float* __restrict__ b7,
    const float* __restrict__ w_out, const float* __restrict__ b_out,
    float* __restrict__ out)
{
  __shared__ __align__(16) float sF[4][32*132];   // per-wave transpose buf, 67.6 KB
  __shared__ __align__(16) float sB[8*128 + 384 + 4];

  const int tid  = threadIdx.x;
  const int lane = tid & 63, wid = tid >> 6;
  const int l31 = lane & 31, lh = lane >> 5;
  const int p0 = blockIdx.x * 128 + wid * 32;

  // stage biases + w_out + b_out (only cross-wave shared data; single barrier)
  {
    const float* bsp[8] = {b0,b1,b2,b3,b4,b5,b6,b7};
    if (tid < 128) {
      #pragma unroll
      for (int l = 0; l < 8; ++l) sB[l*128 + tid] = bsp[l][tid];
    }
    for (int i = tid; i < 384; i += 256) sB[1024 + i] = w_out[i];
    if (tid < 3) sB[1408 + tid] = b_out[tid];
  }

  const uint_t* __restrict__ fr = feat + (size_t)(p0 + l31) * FSTR;

  bf16x8 Xh[8], Xl[8];
  bf16x8 wbh[2][4], wbl[2][4];
  f32x16 acc[4];

  // prime the weight pipeline (p0 slabs 0,1), then feat loads + unpack cover latency
  load_slab(wbh[0], wbl[0], wsWh, wsWl, 0, l31, lh);
  load_slab(wbh[1], wbl[1], wsWh, wsWl, 1, l31, lh);
  load_feat_frags(fr, Xh, Xl, lh);
  __syncthreads();   // sB ready (placed after load issue so it doesn't serialize them)

  // L0 (panel 0, 7 slabs) -> preloads p1
  zero4(acc);
  run_panel<7,true>(acc, wsWh + 0*16384, wsWl + 0*16384,
                         wsWh + 1*16384, wsWl + 1*16384, wbh, wbl, Xh, Xl, l31, lh);
  bias_relu(acc, sB + 0*128, lh);
  build_frags(acc, Xh, Xl, lh);

  // L1 (p1) -> preloads p2
  zero4(acc);
  run_panel<8,true>(acc, wsWh + 1*16384, wsWl + 1*16384,
                         wsWh + 2*16384, wsWl + 2*16384, wbh, wbl, Xh, Xl, l31, lh);
  bias_relu(acc, sB + 1*128, lh);
  build_frags(acc, Xh, Xl, lh);

  // L2 (p2) -> preloads p3
  zero4(acc);
  run_panel<8,true>(acc, wsWh + 2*16384, wsWl + 2*16384,
                         wsWh + 3*16384, wsWl + 3*16384, wbh, wbl, Xh, Xl, l31, lh);
  bias_relu(acc, sB + 2*128, lh);
  build_frags(acc, Xh, Xl, lh);

  // L3 (p3) -> preloads p5 (L4's x-part comes first)
  zero4(acc);
  run_panel<8,true>(acc, wsWh + 3*16384, wsWl + 3*16384,
                         wsWh + 5*16384, wsWl + 5*16384, wbh, wbl, Xh, Xl, l31, lh);
  bias_relu(acc, sB + 3*128, lh);
  build_frags(acc, Xh, Xl, lh);

  // L4 x-part (p5) -> preloads p4; then reload initial feats, accumulate p4 -> preloads p6
  zero4(acc);
  run_panel<8,true>(acc, wsWh + 5*16384, wsWl + 5*16384,
                         wsWh + 4*16384, wsWl + 4*16384, wbh, wbl, Xh, Xl, l31, lh);
  load_feat_frags(fr, Xh, Xl, lh);            // Xh/Xl free to reuse now
  run_panel<7,true>(acc, wsWh + 4*16384, wsWl + 4*16384,
                         wsWh + 6*16384, wsWl + 6*16384, wbh, wbl, Xh, Xl, l31, lh);
  bias_relu(acc, sB + 4*128, lh);
  build_frags(acc, Xh, Xl, lh);

  // L5 (p6) -> preloads p7
  zero4(acc);
  run_panel<8,true>(acc, wsWh + 6*16384, wsWl + 6*16384,
                         wsWh + 7*16384, wsWl + 7*16384, wbh, wbl, Xh, Xl, l31, lh);
  bias_relu(acc, sB + 5*128, lh);
  build_frags(acc, Xh, Xl, lh);

  // L6 (p7) -> preloads p8
  zero4(acc);
  run_panel<8,true>(acc, wsWh + 7*16384, wsWl + 7*16384,
                         wsWh + 8*16384, wsWl + 8*16384, wbh, wbl, Xh, Xl, l31, lh);
  bias_relu(acc, sB + 6*128, lh);
  build_frags(acc, Xh, Xl, lh);

  // L7 (p8, last): pre-activation = last_feat
  zero4(acc);
  run_panel<8,false>(acc, wsWh + 8*16384, wsWl + 8*16384,
                          (const ushort_t*)0, (const ushort_t*)0, wbh, wbl, Xh, Xl, l31, lh);

  // epilogue: +bias -> sF (pre-act, per-wave), relu in acc
  float* __restrict__ sFw = &sF[wid][0];
  #pragma unroll
  for (int tn = 0; tn < 4; ++tn)
    #pragma unroll
    for (int b = 0; b < 4; ++b) {
      const int n0 = tn*32 + 8*b + 4*lh;
      const float4 bv = *(const float4*)(sB + 7*128 + n0);
      const float v0 = acc[tn][4*b+0] + bv.x;
      const float v1 = acc[tn][4*b+1] + bv.y;
      const float v2 = acc[tn][4*b+2] + bv.z;
      const float v3 = acc[tn][4*b+3] + bv.w;
      *(float4*)(sFw + l31*132 + n0) = make_float4(v0, v1, v2, v3);
      acc[tn][4*b+0] = fmaxf(v0, 0.f);
      acc[tn][4*b+1] = fmaxf(v1, 0.f);
      acc[tn][4*b+2] = fmaxf(v2, 0.f);
      acc[tn][4*b+3] = fmaxf(v3, 0.f);
    }

  // within-wave LDS write->read ordering
  asm volatile("s_waitcnt lgkmcnt(0)" ::: "memory");
  __builtin_amdgcn_sched_barrier(0);

  // coalesced fp32 last_feat store
  float* __restrict__ out1 = out + (size_t)NPTS * 3;
  #pragma unroll
  for (int i = 0; i < 16; ++i) {
    const int idx = i*64 + lane;
    const int p = idx >> 5, q = idx & 31;
    const float4 v = *(const float4*)(sFw + p*132 + q*4);
    *(float4*)(out1 + (size_t)(p0 + p)*128 + q*4) = v;
  }

  // mlp_shift = relu(last_feat) . w_out  (in-register partial + half-wave reduce)
  float dotc[3];
  #pragma unroll
  for (int c = 0; c < 3; ++c) {
    float a = 0.f;
    #pragma unroll
    for (int tn = 0; tn < 4; ++tn)
      #pragma unroll
      for (int b = 0; b < 4; ++b) {
        const int n0 = tn*32 + 8*b + 4*lh;
        const float4 w4 = *(const float4*)(sB + 1024 + c*128 + n0);
        a = fmaf(acc[tn][4*b+0], w4.x, a);
        a = fmaf(acc[tn][4*b+1], w4.y, a);
        a = fmaf(acc[tn][4*b+2], w4.z, a);
        a = fmaf(acc[tn][4*b+3], w4.w, a);
      }
    a += __shfl_xor(a, 32, 64);
    dotc[c] = a;
  }
  if (lh == 0) {
    const int g = p0 + l31;
    #pragma unroll
    for (int c = 0; c < 3; ++c)
      out[g*3 + c] = base3[g*3 + c] + dotc[c] + sB[1408 + c];
  }
}

extern "C" void kernel_launch(void* const* d_in, const int* in_sizes, int n_in,
                              void* d_out, int out_size, void* d_ws, size_t ws_size,
                              hipStream_t stream)
{
  const float* pts  = (const float*)d_in[0];
  const float* dm   = (const float*)d_in[1];
  const float* cano = (const float*)d_in[2];
  const float* lat  = (const float*)d_in[3];
  const float* w[8]; const float* b[8];
  for (int i = 0; i < 8; ++i) {
    w[i] = (const float*)d_in[4 + 2*i];
    b[i] = (const float*)d_in[5 + 2*i];
  }
  const float* w_out = (const float*)d_in[20];
  const float* b_out = (const float*)d_in[21];
  float* out = (float*)d_out;

  // ws: feat [NPTS][112] uint (29.36MB) | base3 (786KB) | wsWh (288KB) | wsWl (288KB)
  uint_t*   feat  = (uint_t*)d_ws;
  float*    base3 = (float*)((char*)d_ws + (size_t)NPTS*FSTR*4);
  ushort_t* wsWh  = (ushort_t*)((char*)base3 + (size_t)NPTS*3*4);
  ushort_t* wsWl  = wsWh + 147456;

  k_nnfeat<<<1024, 256, 0, stream>>>(pts, dm, cano, lat,
      w[0],w[1],w[2],w[3],w[4],w[5],w[6],w[7], feat, base3, wsWh, wsWl);
  k_mlp<<<NPTS/128, 256, 0, stream>>>(feat, base3, wsWh, wsWl,
      b[0],b[1],b[2],b[3],b[4],b[5],b[6],b[7], w_out, b_out, out);
}